// Round 1
// baseline (464.582 us; speedup 1.0000x reference)
//
#include <hip/hip_runtime.h>
#include <math.h>

#define NB 8
#define NS 4
#define NP 4096
#define HID 4096
#define NHQ 32
#define NHKV 8
#define ND 128
#define NGROUP 4
#define NBS 32      /* NB*NS rows */
#define NQI 16      /* NGROUP*NS q-rows per (b,kv) */
#define NCHUNK 17   /* 16 cache chunks of 256 + 1 new-token chunk */
#define TCHUNK 256
#define QKV_COLS 6144
#define LOG2E 1.4426950408889634f

// ---------------- transpose x (32 x 4096) -> xT (4096 x 32) ----------------
__global__ __launch_bounds__(256) void prep_xT(const float* __restrict__ x,
                                               float* __restrict__ xT) {
  int n = blockIdx.x * 256 + threadIdx.x;  // n < 131072
  int r = n >> 12;
  int k = n & 4095;
  xT[k * NBS + r] = x[n];
}

// ---------------- RoPE: q -> q_t[(b,kv)][d][i], k_new -> [(b,kv)][s][d] ----
__global__ __launch_bounds__(256) void rope_kernel(
    const float* __restrict__ qb, const float* __restrict__ kb,
    const float* __restrict__ cosp, const float* __restrict__ sinp,
    const int* __restrict__ past_len, float* __restrict__ q_t,
    float* __restrict__ k_new) {
  int n = blockIdx.x * 256 + threadIdx.x;
  int pl = past_len[0];
  if (n < NBS * HID) {  // q element
    int r = n >> 12;    // b*4+s
    int hd = n & 4095;
    int h = hd >> 7, d = hd & 127;
    int b = r >> 2, s = r & 3;
    int pos = pl + s;
    float c = cosp[pos * ND + d], sn = sinp[pos * ND + d];
    float v = qb[n];
    float other = (d < 64) ? -qb[n + 64] : qb[n - 64];
    float rv = fmaf(v, c, other * sn);
    int kv = h >> 2, g = h & 3;
    q_t[(((b * NHKV + kv) * ND + d) * NQI) + g * NS + s] = rv;
  } else {  // k element
    n -= NBS * HID;  // n < 32768
    int r = n >> 10;
    int hd = n & 1023;
    int kv = hd >> 7, d = hd & 127;
    int b = r >> 2, s = r & 3;
    int pos = pl + s;
    float c = cosp[pos * ND + d], sn = sinp[pos * ND + d];
    float v = kb[n];
    float other = (d < 64) ? -kb[n + 64] : kb[n - 64];
    k_new[((b * NHKV + kv) * NS + s) * ND + d] = fmaf(v, c, other * sn);
  }
}

// -------- GEMM partials: P[kb][32][ncols] = A_T-slice x W-slice ------------
// 256 thr = 4 waves; each wave owns KSLICE/4 k-rows x 128 cols.
// Half-wave split over m (lanes 0-31: rows 0-15, lanes 32-63: rows 16-31);
// each lane loads float4 of W (16 B) with rolling depth-8 prefetch ->
// ~8 KB/wave in flight. x-slice staged in LDS (broadcast ds_read_b128).
template <int KSLICE>
__global__ __launch_bounds__(256) void gemm_part(
    const float* __restrict__ A_T, const float* __restrict__ wq,
    const float* __restrict__ wk, const float* __restrict__ wv,
    const float* __restrict__ wo, float* __restrict__ P, int mode) {
  __shared__ __align__(16) float lds[8192];  // x-stage, then tree-reduce (32KB)
  int cb = blockIdx.x, kb = blockIdx.y;
  int ncols = mode ? 4096 : QKV_COLS;
  int col0 = cb * 128;
  const float* W;
  int ld, wcol;
  if (mode) {
    W = wo; ld = 4096; wcol = col0;
  } else if (col0 < 4096) {
    W = wq; ld = 4096; wcol = col0;
  } else if (col0 < 5120) {
    W = wk; ld = 1024; wcol = col0 - 4096;
  } else {
    W = wv; ld = 1024; wcol = col0 - 5120;
  }
  int tid = threadIdx.x;
  int lane = tid & 63;
  int wid = __builtin_amdgcn_readfirstlane(tid >> 6);
  int l32 = lane & 31;
  int mh = lane >> 5;  // m-half: 0 -> rows 0-15, 1 -> rows 16-31
  int kblk = kb * KSLICE;
  constexpr int KW = KSLICE / 4;
  int k0 = wid * KW;
  const float* wp = W + (size_t)(kblk + k0) * ld + wcol + l32 * 4;

  // issue W prefetch first (8 x float4 in flight per lane)
  float4 wb[8];
#pragma unroll
  for (int u = 0; u < 8; u++) wb[u] = *(const float4*)(wp + (size_t)u * ld);

  // stage x-slice (KSLICE x 32) into LDS, coalesced
  {
    const float4* src = (const float4*)(A_T + (size_t)kblk * NBS);
    float4* dst = (float4*)lds;
#pragma unroll
    for (int p = 0; p < KSLICE / 32; p++)
      dst[p * 256 + tid] = src[p * 256 + tid];
  }
  __syncthreads();

  float acc[64];
#pragma unroll
  for (int v = 0; v < 64; v++) acc[v] = 0.f;

  const float* xp = lds + (size_t)k0 * NBS + mh * 16;

  auto body = [&](int kk, float4 w) {
    const float* xr = xp + (size_t)kk * NBS;
    float4 xa = *(const float4*)(xr);
    float4 xb = *(const float4*)(xr + 4);
    float4 xc = *(const float4*)(xr + 8);
    float4 xd = *(const float4*)(xr + 12);
    float xm[16] = {xa.x, xa.y, xa.z, xa.w, xb.x, xb.y, xb.z, xb.w,
                    xc.x, xc.y, xc.z, xc.w, xd.x, xd.y, xd.z, xd.w};
#pragma unroll
    for (int m = 0; m < 16; m++) {
      acc[4 * m + 0] = fmaf(xm[m], w.x, acc[4 * m + 0]);
      acc[4 * m + 1] = fmaf(xm[m], w.y, acc[4 * m + 1]);
      acc[4 * m + 2] = fmaf(xm[m], w.z, acc[4 * m + 2]);
      acc[4 * m + 3] = fmaf(xm[m], w.w, acc[4 * m + 3]);
    }
  };

#pragma unroll 8
  for (int kk = 0; kk < KW - 8; kk++) {
    float4 w = wb[kk & 7];
    wb[kk & 7] = *(const float4*)(wp + (size_t)(kk + 8) * ld);  // prefetch
    body(kk, w);
  }
#pragma unroll
  for (int kk = KW - 8; kk < KW; kk++) {  // drain tail, no prefetch
    float4 w = wb[kk & 7];
    body(kk, w);
  }

  __syncthreads();  // x-stage dead -> reuse LDS as reduce buffer
  if (wid >= 2) {
#pragma unroll
    for (int v = 0; v < 64; v++) lds[(wid - 2) * 4096 + v * 64 + lane] = acc[v];
  }
  __syncthreads();
  if (wid < 2) {
#pragma unroll
    for (int v = 0; v < 64; v++) acc[v] += lds[wid * 4096 + v * 64 + lane];
  }
  __syncthreads();
  if (wid == 1) {
#pragma unroll
    for (int v = 0; v < 64; v++) lds[v * 64 + lane] = acc[v];
  }
  __syncthreads();
  if (wid == 0) {
#pragma unroll
    for (int v = 0; v < 64; v++) acc[v] += lds[v * 64 + lane];
#pragma unroll
    for (int m = 0; m < 16; m++) {
      float4 st = make_float4(acc[4 * m], acc[4 * m + 1], acc[4 * m + 2],
                              acc[4 * m + 3]);
      *(float4*)(P + ((size_t)kb * NBS + mh * 16 + m) * ncols + col0 +
                 l32 * 4) = st;
    }
  }
}

// ---------------- reduce partials: qkv -> qb/kb/vb -------------------------
template <int KS>
__global__ __launch_bounds__(256) void reduce_qkv(const float* __restrict__ P,
                                                  float* __restrict__ qb,
                                                  float* __restrict__ kbuf,
                                                  float* __restrict__ vbuf) {
  size_t idx = ((size_t)blockIdx.x * 256 + threadIdx.x) * 4;  // < 196608
  float4 s = make_float4(0.f, 0.f, 0.f, 0.f);
#pragma unroll
  for (int p = 0; p < KS; p++) {
    float4 v = *(const float4*)(P + (size_t)p * (NBS * QKV_COLS) + idx);
    s.x += v.x; s.y += v.y; s.z += v.z; s.w += v.w;
  }
  int r = (int)(idx / QKV_COLS);
  int col = (int)(idx % QKV_COLS);
  float* dst;
  if (col < 4096)
    dst = qb + (size_t)r * 4096 + col;
  else if (col < 5120)
    dst = kbuf + (size_t)r * 1024 + (col - 4096);
  else
    dst = vbuf + (size_t)r * 1024 + (col - 5120);
  *(float4*)dst = s;
}

// ---------------- reduce partials: out-proj -> out -------------------------
template <int KS>
__global__ __launch_bounds__(256) void reduce_o(const float* __restrict__ P,
                                                float* __restrict__ outp) {
  size_t idx = ((size_t)blockIdx.x * 256 + threadIdx.x) * 4;  // < 131072
  float4 s = make_float4(0.f, 0.f, 0.f, 0.f);
#pragma unroll
  for (int p = 0; p < KS; p++) {
    float4 v = *(const float4*)(P + (size_t)p * (NBS * 4096) + idx);
    s.x += v.x; s.y += v.y; s.z += v.z; s.w += v.w;
  }
  *(float4*)(outp + idx) = s;
}

// ---------------- attention: grid = (bk, chunk), 256 threads ---------------
// Phase 1 (scores): thread t, full d — unchanged.
// Phase 2 (PV): 8 groups of 32 lanes each own 32 tokens; thread accumulates
// all 16 q-rows x 4 d (64 VGPR). V loads: 32/thread (was 256), zero
// redundancy. shfl fold + 2-stage LDS tree (reuses transposed p-buffer).
__global__ __launch_bounds__(256) void attn_kernel(
    const float* __restrict__ q_t, const float* __restrict__ k_cache,
    const float* __restrict__ v_cache, const float* __restrict__ k_new,
    const float* __restrict__ vbuf, float* __restrict__ part_o,
    float* __restrict__ part_m, float* __restrict__ part_l) {
  __shared__ __align__(16) float sbuf[NQI * TCHUNK];  // p[i][t] then reduce
  __shared__ float redm[NQI][4];
  __shared__ float redl[NQI][4];
  __shared__ float mfin[NQI];
  float* p_lds = sbuf;
  int bk = blockIdx.x;
  int chunk = blockIdx.y;
  int blk = bk * NCHUNK + chunk;
  int b = bk >> 3, kv = bk & 7;
  int tid = threadIdx.x;
  int lane = tid & 63;
  int wid = tid >> 6;
  bool last = (chunk == NCHUNK - 1);
  int tcount = last ? NS : TCHUNK;
  const float* qbase = q_t + (size_t)bk * (ND * NQI);

  // ---- scores: one thread per t, full d ----
  int t_loc = tid;
  bool valid = t_loc < tcount;
  int t_eff = valid ? t_loc : 0;
  const float* kp =
      last ? (k_new + ((size_t)bk * NS + t_eff) * ND)
           : (k_cache +
              (((size_t)b * NP + chunk * TCHUNK + t_eff) * NHKV + kv) * ND);
  float s_acc[NQI];
#pragma unroll
  for (int i = 0; i < NQI; i++) s_acc[i] = 0.f;
#pragma unroll 8
  for (int d4 = 0; d4 < 32; ++d4) {
    float4 kvv = *(const float4*)(kp + d4 * 4);
    const float* qp = qbase + (d4 * 4) * NQI;  // uniform -> s_load
#pragma unroll
    for (int i = 0; i < NQI; i++) {
      float s = s_acc[i];
      s = fmaf(kvv.x, qp[i], s);
      s = fmaf(kvv.y, qp[NQI + i], s);
      s = fmaf(kvv.z, qp[2 * NQI + i], s);
      s = fmaf(kvv.w, qp[3 * NQI + i], s);
      s_acc[i] = s;
    }
  }
  const float scale = 0.08838834764831845f;  // 1/sqrt(128)
  float sc[NQI];
#pragma unroll
  for (int i = 0; i < NQI; i++) {
    float s = s_acc[i] * scale;
    if (!valid || (last && t_loc > (i & 3))) s = -__builtin_inff();
    sc[i] = s;
  }
#pragma unroll
  for (int i = 0; i < NQI; i++) {
    float m = sc[i];
#pragma unroll
    for (int off = 1; off < 64; off <<= 1) m = fmaxf(m, __shfl_xor(m, off, 64));
    if (lane == 0) redm[i][wid] = m;
  }
  __syncthreads();
  if (tid < NQI) {
    mfin[tid] = fmaxf(fmaxf(redm[tid][0], redm[tid][1]),
                      fmaxf(redm[tid][2], redm[tid][3]));
  }
  __syncthreads();
  float l_loc[NQI];
#pragma unroll
  for (int i = 0; i < NQI; i++) {
    float p = exp2f((sc[i] - mfin[i]) * LOG2E);
    p_lds[i * TCHUNK + t_loc] = p;  // transposed: consecutive lanes -> banks
    l_loc[i] = p;
  }
#pragma unroll
  for (int i = 0; i < NQI; i++) {
    float l = l_loc[i];
#pragma unroll
    for (int off = 1; off < 64; off <<= 1) l += __shfl_xor(l, off, 64);
    if (lane == 0) redl[i][wid] = l;
  }
  __syncthreads();  // also publishes p_lds for PV
  if (tid < NQI) {
    part_m[(size_t)blk * NQI + tid] = mfin[tid];
    part_l[(size_t)blk * NQI + tid] =
        redl[tid][0] + redl[tid][1] + redl[tid][2] + redl[tid][3];
  }

  // ---- PV: group g (32 lanes) owns t in [32g, 32g+32); thread: 16q x 4d ---
  int g = tid >> 5;
  int dq = (tid & 31) * 4;
  int tbeg = g * 32;
  int tnum = tcount - tbeg;
  tnum = tnum < 0 ? 0 : (tnum > 32 ? 32 : tnum);
  const float* vpb =
      last ? (vbuf + ((size_t)b * NS + tbeg) * (NHKV * ND) + kv * ND + dq)
           : (v_cache + ((size_t)b * NP + chunk * TCHUNK + tbeg) * (NHKV * ND) +
              kv * ND + dq);
  float o[NQI][4];
#pragma unroll
  for (int i = 0; i < NQI; i++) o[i][0] = o[i][1] = o[i][2] = o[i][3] = 0.f;
#pragma unroll 4
  for (int tt = 0; tt < tnum; ++tt) {
    float4 vv = *(const float4*)(vpb + (size_t)tt * (NHKV * ND));
    const float* pp = p_lds + (tbeg + tt);
#pragma unroll
    for (int i = 0; i < NQI; i++) {
      float p = pp[i * TCHUNK];  // group-uniform -> LDS broadcast
      o[i][0] = fmaf(p, vv.x, o[i][0]);
      o[i][1] = fmaf(p, vv.y, o[i][1]);
      o[i][2] = fmaf(p, vv.z, o[i][2]);
      o[i][3] = fmaf(p, vv.w, o[i][3]);
    }
  }
  // fold the two 32-lane groups of each wave (t-halves)
#pragma unroll
  for (int i = 0; i < NQI; i++) {
#pragma unroll
    for (int c = 0; c < 4; c++) o[i][c] += __shfl_xor(o[i][c], 32, 64);
  }
  __syncthreads();  // p_lds dead -> sbuf becomes reduce buffer
  float* red = sbuf;
  if (wid >= 2 && lane < 32) {
#pragma unroll
    for (int i = 0; i < NQI; i++)
      *(float4*)(red + ((wid - 2) * NQI + i) * 128 + dq) =
          make_float4(o[i][0], o[i][1], o[i][2], o[i][3]);
  }
  __syncthreads();
  if (wid < 2 && lane < 32) {
#pragma unroll
    for (int i = 0; i < NQI; i++) {
      float4 r = *(const float4*)(red + (wid * NQI + i) * 128 + dq);
      o[i][0] += r.x; o[i][1] += r.y; o[i][2] += r.z; o[i][3] += r.w;
    }
  }
  __syncthreads();
  if (wid == 1 && lane < 32) {
#pragma unroll
    for (int i = 0; i < NQI; i++)
      *(float4*)(red + i * 128 + dq) =
          make_float4(o[i][0], o[i][1], o[i][2], o[i][3]);
  }
  __syncthreads();
  if (wid == 0 && lane < 32) {
    size_t obase = (size_t)blk * (NQI * ND);
#pragma unroll
    for (int i = 0; i < NQI; i++) {
      float4 r = *(const float4*)(red + i * 128 + dq);
      *(float4*)(part_o + obase + (size_t)i * ND + dq) =
          make_float4(o[i][0] + r.x, o[i][1] + r.y, o[i][2] + r.z,
                      o[i][3] + r.w);
    }
  }
}

// ---------------- combine partials -> attn_T (4096 x 32) -------------------
__global__ __launch_bounds__(256) void combine_kernel(
    const float* __restrict__ part_o, const float* __restrict__ part_m,
    const float* __restrict__ part_l, float* __restrict__ attn_T) {
  int bk = blockIdx.x;
  int tid = threadIdx.x;
  int i = tid >> 4;
  int dh = (tid & 15) * 4 + blockIdx.y * 64;
  float M = -__builtin_inff();
#pragma unroll
  for (int c = 0; c < NCHUNK; c++)
    M = fmaxf(M, part_m[((size_t)bk * NCHUNK + c) * NQI + i]);
  float L = 0.f;
  float o0 = 0.f, o1 = 0.f, o2 = 0.f, o3 = 0.f;
#pragma unroll
  for (int c = 0; c < NCHUNK; c++) {
    size_t pc = (size_t)bk * NCHUNK + c;
    float mc = part_m[pc * NQI + i];
    float w = exp2f((mc - M) * LOG2E);
    L = fmaf(part_l[pc * NQI + i], w, L);
    float4 po = *(const float4*)(part_o + pc * (NQI * ND) + (size_t)i * ND + dh);
    o0 = fmaf(w, po.x, o0);
    o1 = fmaf(w, po.y, o1);
    o2 = fmaf(w, po.z, o2);
    o3 = fmaf(w, po.w, o3);
  }
  float inv = 1.0f / L;
  int b = bk >> 3, kv = bk & 7;
  int g = i >> 2, s = i & 3;
  int h = kv * NGROUP + g;
  int r = b * NS + s;
  attn_T[(size_t)(h * ND + dh + 0) * NBS + r] = o0 * inv;
  attn_T[(size_t)(h * ND + dh + 1) * NBS + r] = o1 * inv;
  attn_T[(size_t)(h * ND + dh + 2) * NBS + r] = o2 * inv;
  attn_T[(size_t)(h * ND + dh + 3) * NBS + r] = o3 * inv;
}

// ---------------------------------------------------------------------------
extern "C" void kernel_launch(void* const* d_in, const int* in_sizes, int n_in,
                              void* d_out, int out_size, void* d_ws,
                              size_t ws_size, hipStream_t stream) {
  const float* x = (const float*)d_in[0];
  const float* wq = (const float*)d_in[1];
  const float* wk = (const float*)d_in[2];
  const float* wv = (const float*)d_in[3];
  const float* wo = (const float*)d_in[4];
  const float* cosp = (const float*)d_in[5];
  const float* sinp = (const float*)d_in[6];
  const float* k_cache = (const float*)d_in[7];
  const float* v_cache = (const float*)d_in[8];
  const int* past_len = (const int*)d_in[9];
  float* out = (float*)d_out;

  float* ws = (float*)d_ws;
  float* xT = ws;                   // 131072
  float* qb = xT + 131072;          // 131072
  float* kbuf = qb + 131072;        // 32768
  float* vbuf = kbuf + 32768;       // 32768
  float* q_t = vbuf + 32768;        // 131072
  float* k_new = q_t + 131072;      // 32768
  float* attn_T = k_new + 32768;    // 131072
  float* R = attn_T + 131072;       // shared region
  float* Pq = R;                    // up to 32*32*6144 (dead after reduce)
  float* part_o = R;                // 64*17*2048 = 2228224 (dead after combine)
  float* part_m = R + 2228224;      // 17408
  float* part_l = part_m + 17408;   // 17408
  float* Po = R;                    // up to 32*32*4096

  // KSPLIT=32 needs 622592 + 32*32*6144 floats of workspace; else fall back.
  const size_t need32 = (size_t)(622592 + 32 * NBS * QKV_COLS) * sizeof(float);
  const bool big = ws_size >= need32;

  prep_xT<<<512, 256, 0, stream>>>(x, xT);
  if (big) {
    gemm_part<128><<<dim3(48, 32), 256, 0, stream>>>(xT, wq, wk, wv, wo, Pq, 0);
    reduce_qkv<32><<<192, 256, 0, stream>>>(Pq, qb, kbuf, vbuf);
  } else {
    gemm_part<256><<<dim3(48, 16), 256, 0, stream>>>(xT, wq, wk, wv, wo, Pq, 0);
    reduce_qkv<16><<<192, 256, 0, stream>>>(Pq, qb, kbuf, vbuf);
  }
  rope_kernel<<<640, 256, 0, stream>>>(qb, kbuf, cosp, sinp, past_len, q_t,
                                       k_new);
  attn_kernel<<<dim3(64, NCHUNK), 256, 0, stream>>>(
      q_t, k_cache, v_cache, k_new, vbuf, part_o, part_m, part_l);
  combine_kernel<<<dim3(64, 2), 256, 0, stream>>>(part_o, part_m, part_l,
                                                  attn_T);
  if (big) {
    gemm_part<128><<<dim3(32, 32), 256, 0, stream>>>(attn_T, wq, wk, wv, wo,
                                                     Po, 1);
    reduce_o<32><<<128, 256, 0, stream>>>(Po, out);
  } else {
    gemm_part<256><<<dim3(32, 16), 256, 0, stream>>>(attn_T, wq, wk, wv, wo,
                                                     Po, 1);
    reduce_o<16><<<128, 256, 0, stream>>>(Po, out);
  }
}